// Round 1
// baseline (264.261 us; speedup 1.0000x reference)
//
#include <hip/hip_runtime.h>
#include <stdint.h>

#define DIM 1024
#define SEQ 2048
#define BATCH 4
#define ROWS (BATCH*SEQ)          /* 8192 */
// attention scale folded into Q: 0.125 * log2(e)
#define QSCALE 0.1803368801111f

typedef __attribute__((ext_vector_type(8))) short bf16x8;   // 8 bf16 in 4 VGPRs
typedef __attribute__((ext_vector_type(4))) float f32x4;
typedef __attribute__((ext_vector_type(8))) _Float16 f16x8;
typedef __attribute__((ext_vector_type(2))) __fp16 fp16x2_raw;  // cvt_pkrtz return type

#if __has_builtin(__builtin_amdgcn_exp2f)
#define EXP2F(x) __builtin_amdgcn_exp2f(x)
#else
#define EXP2F(x) __expf((x) * 0.69314718056f)
#endif

#define MFMA_BF16_K32(a,b,c) __builtin_amdgcn_mfma_f32_16x16x32_bf16(a,b,c,0,0,0)
#define MFMA_F16_K32(a,b,c)  __builtin_amdgcn_mfma_f32_16x16x32_f16(a,b,c,0,0,0)

// ---- fp32 -> bf16 RNE ----
__device__ __forceinline__ unsigned short f2bf(float f) {
  union { float f; unsigned int u; } v; v.f = f;
  unsigned int u = v.u;
  return (unsigned short)((u + 0x7FFFu + ((u >> 16) & 1u)) >> 16);
}

// ---- fp32 -> fp16 RNE (bits) ----
__device__ __forceinline__ unsigned short f2h(float f) {
  union { _Float16 h; unsigned short u; } v;
  v.h = (_Float16)f;
  return v.u;
}

// pack two f32 -> fp16x2 dword (v_cvt_pkrtz_f16_f32), returned as raw bits
__device__ __forceinline__ unsigned int pkrtz_bits(float lo, float hi) {
  union { fp16x2_raw h; unsigned int u; } v;
  v.h = __builtin_amdgcn_cvt_pkrtz(lo, hi);
  return v.u;
}

// ---- async global->LDS, 16B per lane (wave-uniform LDS base + lane*16) ----
__device__ __forceinline__ void gload_lds16(const void* g, void* l) {
  __builtin_amdgcn_global_load_lds(
      (const __attribute__((address_space(1))) unsigned int*)g,
      (__attribute__((address_space(3))) unsigned int*)l,
      16, 0, 0);
}

// ---- fused cast kernel: x (8M) | w_qkv (3M) | w_proj (1M) fp32 -> bf16 ----
__global__ void cast_all(const float* __restrict__ x,
                         const float* __restrict__ wq,
                         const float* __restrict__ wp,
                         unsigned short* __restrict__ xb,
                         unsigned short* __restrict__ wqb,
                         unsigned short* __restrict__ wpb) {
  const int i = (blockIdx.x * blockDim.x + threadIdx.x) * 4;
  const float* src;
  unsigned short* dst;
  int off;
  if (i < ROWS * DIM)                 { src = x;  dst = xb;  off = i; }
  else if (i < ROWS * DIM + 3 * DIM * DIM) { src = wq; dst = wqb; off = i - ROWS * DIM; }
  else                                { src = wp; dst = wpb; off = i - ROWS * DIM - 3 * DIM * DIM; }
  float4 f = *(const float4*)(src + off);
  ushort4 o;
  o.x = f2bf(f.x); o.y = f2bf(f.y); o.z = f2bf(f.z); o.w = f2bf(f.w);
  *(ushort4*)(dst + off) = o;
}

// swapped/normal MFMA helper (SWAP transposes the C fragment)
template<int SWAP>
__device__ __forceinline__ f32x4 mm(bf16x8 a, bf16x8 b, f32x4 c) {
  if constexpr (SWAP) return __builtin_amdgcn_mfma_f32_16x16x32_bf16(b, a, c, 0, 0, 0);
  else                return __builtin_amdgcn_mfma_f32_16x16x32_bf16(a, b, c, 0, 0, 0);
}

// ---- 8-phase 256x256 QKV GEMM (T2+T3+T4+T5 template, plain HIP) ----
// C[8192, n0..n0+256) = X @ Wqkv^T over K=1024 (16 K-tiles of 64).
// SWAP=1: Q/K columns (n0 in [0,2048)), transposed C frags -> vectorized
//         [bh][n][d] ushort4 writes (Q scaled by QSCALE).
// SWAP=0: V columns (n0 in [2048,3072)), normal C frags -> vectorized
//         V^T [bh][d][n] fp16 ushort4 writes.
// Schedule per K-tile t (reads buf=t&1, stages tile t+2 into same buf as
// regions free; tile t+1's B-h1 staged at (t,P1) into buf^1):
//   P1: ds A[MH0](8)+B[NH0](4) | stg B-h1(t+1) | bar lgkm mfma(mi0-3,ni0-1) bar
//   P2: ds B[NH1](4)           | stg A-r1(t+2) | bar lgkm mfma(mi0-3,ni2-3) bar
//   P3: ds A[MH1](8)           | stg B-h0(t+2) | bar lgkm mfma(mi4-7,ni2-3) bar
//   P4:                        | stg A-r2(t+2) | vmcnt(6) bar mfma(mi4-7,ni0-1) bar
// vmcnt(6) leaves tile t+2's 6 newest loads in flight (never drains to 0).
// LDS rows are 128B -> XOR swizzle chunk^=(row&7), applied as pre-swizzled
// GLOBAL source (gload_lds writes linearly) + swizzled ds_read address.
template<int SWAP, int NTX>
__global__ __launch_bounds__(512, 2) void gemm_qkv8(
    const unsigned short* __restrict__ A,    // [8192][1024] bf16
    const unsigned short* __restrict__ W,    // [3072][1024] bf16
    unsigned short* __restrict__ qb,
    unsigned short* __restrict__ kb,
    unsigned short* __restrict__ vtb) {
  constexpr int K = DIM;
  constexpr int NT = K / 64;                 // 16 K-tiles
  constexpr int N0B = SWAP ? 0 : 2048;
  __shared__ unsigned short Al[2][256 * 64]; // 64KB
  __shared__ unsigned short Bl[2][256 * 64]; // 64KB

  const int tid  = threadIdx.x;
  const int wave = tid >> 6, lane = tid & 63;
  const int quad = lane >> 4, l16 = lane & 15;
  const int wm = wave >> 2, wn = wave & 3;   // 2 x 4 wave grid

  // XCD-bijective block swizzle (nwg % 8 == 0 for both grids)
  constexpr int nwg = NTX * 32;
  int id = blockIdx.y * NTX + blockIdx.x;
  id = (id & 7) * (nwg >> 3) + (id >> 3);
  const int bx = id % NTX, by = id / NTX;
  const int m0 = by * 256, n0 = N0B + bx * 256;

  // staging addresses: lane -> (row = wave*8 + lane>>3, src chunk pre-swizzled)
  const int srow8 = lane >> 3;               // 0..7, == (lds row & 7)
  const int schk  = (lane & 7) ^ srow8;      // involution: lds chunk ^ row&7
  const unsigned short* Ast = A + (size_t)(m0 + wave * 8 + srow8) * K + (schk << 3);
  const unsigned short* Bst = W + (size_t)(n0 + wave * 8 + srow8) * K + (schk << 3);

  // one block-wide 64-row slab load: 1 gload_lds per wave (8 rows/wave)
  auto stg = [&](const unsigned short* g, int R0, int kt, unsigned short* l) {
    gload_lds16((const void*)(g + (size_t)R0 * K + kt),
                (void*)(l + (R0 + wave * 8) * 64));
  };
  // swizzled fragment read: row rb+idx*16+l16, k-chunk kk*4+quad
  auto ldf = [&](const unsigned short* base, int rb, int idx, int kk) -> bf16x8 {
    const int r = rb + idx * 16 + l16;
    return *(const bf16x8*)&base[r * 64 + (((kk * 4 + quad) ^ (l16 & 7)) << 3)];
  };

  f32x4 acc[8][4];
#pragma unroll
  for (int i = 0; i < 8; ++i)
#pragma unroll
    for (int j = 0; j < 4; ++j) acc[i][j] = (f32x4)0.f;

  // prologue: tile 0 complete (8 loads, oldest), tile 1 all but B-h1 (6)
  stg(Ast, 0, 0, Al[0]);  stg(Ast, 128, 0, Al[0]);
  stg(Ast, 64, 0, Al[0]); stg(Ast, 192, 0, Al[0]);
  stg(Bst, 0, 0, Bl[0]);  stg(Bst, 64, 0, Bl[0]);
  stg(Bst, 128, 0, Bl[0]); stg(Bst, 192, 0, Bl[0]);
  stg(Ast, 0, 64, Al[1]);  stg(Ast, 128, 64, Al[1]);
  stg(Bst, 0, 64, Bl[1]);  stg(Bst, 64, 64, Bl[1]);
  stg(Ast, 64, 64, Al[1]); stg(Ast, 192, 64, Al[1]);
  asm volatile("s_waitcnt vmcnt(6)" ::: "memory");  // tile 0 landed
  __builtin_amdgcn_s_barrier();

  bf16x8 af[4][2], bf[4][2];
  int buf = 0;
  for (int t = 0; t < NT; ++t, buf ^= 1) {
    const unsigned short* Ac = Al[buf];
    const unsigned short* Bc = Bl[buf];
    unsigned short* Asg = Al[buf];   // tile t+2 reuses current buffer
    unsigned short* Bsg = Bl[buf];
    const int kt2 = (t + 2) * 64;

    // ---------- P1 ----------
#pragma unroll
    for (int mi = 0; mi < 4; ++mi) {
      af[mi][0] = ldf(Ac, wm * 128, mi, 0);
      af[mi][1] = ldf(Ac, wm * 128, mi, 1);
    }
#pragma unroll
    for (int ni = 0; ni < 2; ++ni) {
      bf[ni][0] = ldf(Bc, wn * 64, ni, 0);
      bf[ni][1] = ldf(Bc, wn * 64, ni, 1);
    }
    if (t + 1 < NT) {  // B-h1 of tile t+1 (region free since tile t-1)
      stg(Bst, 128, (t + 1) * 64, Bl[buf ^ 1]);
      stg(Bst, 192, (t + 1) * 64, Bl[buf ^ 1]);
    }
    __builtin_amdgcn_s_barrier();
    asm volatile("s_waitcnt lgkmcnt(0)" ::: "memory");
    __builtin_amdgcn_s_setprio(1);
#pragma unroll
    for (int mi = 0; mi < 4; ++mi)
#pragma unroll
      for (int ni = 0; ni < 2; ++ni)
#pragma unroll
        for (int kk = 0; kk < 2; ++kk)
          acc[mi][ni] = mm<SWAP>(af[mi][kk], bf[ni][kk], acc[mi][ni]);
    __builtin_amdgcn_s_setprio(0);
    __builtin_amdgcn_s_barrier();

    // ---------- P2 ----------
#pragma unroll
    for (int ni = 2; ni < 4; ++ni) {
      bf[ni][0] = ldf(Bc, wn * 64, ni, 0);
      bf[ni][1] = ldf(Bc, wn * 64, ni, 1);
    }
    if (t + 2 < NT) {  // A rows {0-63,128-191}: freed by P1
      stg(Ast, 0, kt2, Asg);
      stg(Ast, 128, kt2, Asg);
    }
    __builtin_amdgcn_s_barrier();
    asm volatile("s_waitcnt lgkmcnt(0)" ::: "memory");
    __builtin_amdgcn_s_setprio(1);
#pragma unroll
    for (int mi = 0; mi < 4; ++mi)
#pragma unroll
      for (int ni = 2; ni < 4; ++ni)
#pragma unroll
        for (int kk = 0; kk < 2; ++kk)
          acc[mi][ni] = mm<SWAP>(af[mi][kk], bf[ni][kk], acc[mi][ni]);
    __builtin_amdgcn_s_setprio(0);
    __builtin_amdgcn_s_barrier();

    // ---------- P3 ----------
#pragma unroll
    for (int mi = 0; mi < 4; ++mi) {
      af[mi][0] = ldf(Ac, wm * 128, mi + 4, 0);
      af[mi][1] = ldf(Ac, wm * 128, mi + 4, 1);
    }
    if (t + 2 < NT) {  // B rows {0-127}: all B freed by P2
      stg(Bst, 0, kt2, Bsg);
      stg(Bst, 64, kt2, Bsg);
    }
    __builtin_amdgcn_s_barrier();
    asm volatile("s_waitcnt lgkmcnt(0)" ::: "memory");
    __builtin_amdgcn_s_setprio(1);
#pragma unroll
    for (int mi = 0; mi < 4; ++mi)
#pragma unroll
      for (int ni = 2; ni < 4; ++ni)
#pragma unroll
        for (int kk = 0; kk < 2; ++kk)
          acc[mi + 4][ni] = mm<SWAP>(af[mi][kk], bf[ni][kk], acc[mi + 4][ni]);
    __builtin_amdgcn_s_setprio(0);
    __builtin_amdgcn_s_barrier();

    // ---------- P4 ----------
    if (t + 2 < NT) {  // A rows {64-127,192-255}: freed by P3
      stg(Ast, 64, kt2, Asg);
      stg(Ast, 192, kt2, Asg);
      asm volatile("s_waitcnt vmcnt(6)" ::: "memory");  // tile t+1 landed
    } else {
      asm volatile("s_waitcnt vmcnt(0)" ::: "memory");
    }
    __builtin_amdgcn_s_barrier();
    __builtin_amdgcn_s_setprio(1);
#pragma unroll
    for (int mi = 0; mi < 4; ++mi)
#pragma unroll
      for (int ni = 0; ni < 2; ++ni)
#pragma unroll
        for (int kk = 0; kk < 2; ++kk)
          acc[mi + 4][ni] = mm<SWAP>(af[mi][kk], bf[ni][kk], acc[mi + 4][ni]);
    __builtin_amdgcn_s_setprio(0);
    __builtin_amdgcn_s_barrier();
  }

  // ---------- epilogue ----------
  if constexpr (SWAP) {
    // transposed frags: lane col=l16 -> token, row=quad*4+r -> feature
    const float sc = (n0 < 1024) ? QSCALE : 1.f;
    unsigned short* base = (n0 < 1024) ? qb : kb;
#pragma unroll
    for (int mi = 0; mi < 8; ++mi) {
      const int tok = m0 + wm * 128 + mi * 16 + l16;
      const int b = tok >> 11, n = tok & 2047;
#pragma unroll
      for (int ni = 0; ni < 4; ++ni) {
        const int f0 = n0 + wn * 64 + ni * 16 + quad * 4;
        const int h = (f0 >> 6) & 15, d = f0 & 63;
        ushort4 o4;
        o4.x = f2bf(acc[mi][ni][0] * sc);
        o4.y = f2bf(acc[mi][ni][1] * sc);
        o4.z = f2bf(acc[mi][ni][2] * sc);
        o4.w = f2bf(acc[mi][ni][3] * sc);
        *(ushort4*)&base[((size_t)(b * 16 + h) * SEQ + n) * 64 + d] = o4;
      }
    }
  } else {
    // normal frags: row=quad*4+r -> token, col=l16 -> feature; V^T fp16
#pragma unroll
    for (int mi = 0; mi < 8; ++mi) {
      const int row = m0 + wm * 128 + mi * 16 + quad * 4;
      const int b = row >> 11, n = row & 2047;
#pragma unroll
      for (int ni = 0; ni < 4; ++ni) {
        const int col = n0 + wn * 64 + ni * 16 + l16;
        const int h = (col >> 6) & 15, d = col & 63;
        ushort4 o4;
        o4.x = f2h(acc[mi][ni][0]); o4.y = f2h(acc[mi][ni][1]);
        o4.z = f2h(acc[mi][ni][2]); o4.w = f2h(acc[mi][ni][3]);
        *(ushort4*)&vtb[((size_t)(b * 16 + h) * 64 + d) * SEQ + n] = o4;
      }
    }
  }
}

// ---- flash attention R7:
// S^T = K*Q^T with PERMUTED key rows: two 16-key tiles T0={8a+b}, T1={8a+4+b}
// per 32-key group, so lane (quad,l16)'s exp'd C-frags concatenate into the
// exact A-frag of mfma_f32_16x16x32_f16 (keys quad*8+0..7). PV at full K=32
// rate, P never touches LDS. Double-buffered K/V, one barrier/iter.
// Grid (bh=64, qtile=8): same-bh blocks land on one XCD (%8) -> L2 reuse.
__global__ __launch_bounds__(256, 2) void attn_kernel(
    const unsigned short* __restrict__ qb,   // [bh][n][d] bf16, pre-scaled by QSCALE
    const unsigned short* __restrict__ kb,   // [bh][n][d] bf16
    const unsigned short* __restrict__ vtb,  // [bh][d][n] fp16
    unsigned short* __restrict__ out) {      // [8192][1024] bf16
  __shared__ unsigned short Kl[2][64 * 64];  // [key][d], chunk c at c^sK(row), sK=(r&3)|((r>>3&1)<<2)
  __shared__ unsigned short Vl[2][64 * 64];  // [d][key] fp16 bits, chunk c at c^(row&7)

  const int tid  = threadIdx.x;
  const int wave = tid >> 6, lane = tid & 63;
  const int quad = lane >> 4, l16 = lane & 15;
  const int bh    = blockIdx.x;           // 0..63  (XCD affinity)
  const int qtile = blockIdx.y;           // 0..7
  const size_t qkbase = (size_t)bh * SEQ * 64;
  const int q0 = qtile * 256 + wave * 64;

  // Q B-frags: Q[n=l16][k=kk*32+quad*8+j]  (kk = d-half here)
  bf16x8 qf[4][2];
#pragma unroll
  for (int mi = 0; mi < 4; mi++)
#pragma unroll
    for (int kk = 0; kk < 2; kk++)
      qf[mi][kk] = *(const bf16x8*)&qb[qkbase + (size_t)(q0 + mi * 16 + l16) * 64 + kk * 32 + quad * 8];

  f32x4 o[4][4];
#pragma unroll
  for (int mi = 0; mi < 4; mi++)
#pragma unroll
    for (int nt = 0; nt < 4; nt++) o[mi][nt] = (f32x4)0.f;
  f32x4 lacc[4];
#pragma unroll
  for (int mi = 0; mi < 4; mi++) lacc[mi] = (f32x4)0.f;

  union { f16x8 v; unsigned int d[4]; } ones8;
#pragma unroll
  for (int j = 0; j < 4; j++) ones8.d[j] = 0x3C003C00u;  // fp16 1.0 x8

  const unsigned short* Kg = kb + qkbase;
  const unsigned short* Vg = vtb + (size_t)bh * 64 * SEQ;
  const int srow = tid >> 3;   // 0..31
  const int schk = tid & 7;
  const int swK = (srow & 3) | (((srow >> 3) & 1) << 2);
  const int swV = srow & 7;

  auto stage = [&](int kt, int buf) {
#pragma unroll
    for (int p = 0; p < 2; p++) {
      const int r = p * 32 + srow;
      gload_lds16((const void*)(Kg + (size_t)(kt + r) * 64 + (schk ^ swK) * 8),
                  (void*)&Kl[buf][p * 2048 + wave * 512]);
      gload_lds16((const void*)(Vg + (size_t)r * SEQ + kt + (schk ^ swV) * 8),
                  (void*)&Vl[buf][p * 2048 + wave * 512]);
    }
  };

  stage(0, 0);

  const int rbase = ((l16 >> 2) << 3) + (l16 & 3);               // 8a + b
  const int sR = (l16 & 3) | (((l16 >> 2) & 1) << 2);            // K read swizzle

  int buf = 0;
  for (int kt = 0; kt < SEQ; kt += 64, buf ^= 1) {
    __syncthreads();  // tile `buf` staged; prev reads of buf^1 done
    if (kt + 64 < SEQ) stage(kt + 64, buf ^ 1);

#pragma unroll
    for (int kk = 0; kk < 2; kk++) {
      // K A-frags, permuted rows: T gives phys keys kk*32 + 8*(l16>>2) + (l16&3) + 4T
      bf16x8 kf[2][2];
#pragma unroll
      for (int T = 0; T < 2; T++) {
        const int R = kk * 32 + rbase + 4 * T;
        kf[T][0] = *(const bf16x8*)&Kl[buf][R * 64 + ((quad ^ sR) << 3)];
        kf[T][1] = *(const bf16x8*)&Kl[buf][R * 64 + (((4 + quad) ^ sR) << 3)];
      }
      // V B-frags: B[n=d=nt*16+l16][k=key=kk*32+quad*8+j]
      f16x8 vf[4];
#pragma unroll
      for (int nt = 0; nt < 4; nt++) {
        const int vr = nt * 16 + l16;
        vf[nt] = *(const f16x8*)&Vl[buf][vr * 64 + (((kk * 4 + quad) ^ (vr & 7)) << 3)];
      }
#pragma unroll
      for (int mi = 0; mi < 4; mi++) {
        // S^T tiles: C[m -> phys key kk*32+8*quad+r(+4T)][n=q=l16]
        f32x4 s0 = (f32x4)0.f, s1 = (f32x4)0.f;
        s0 = MFMA_BF16_K32(kf[0][0], qf[mi][0], s0);
        s0 = MFMA_BF16_K32(kf[0][1], qf[mi][1], s0);
        s1 = MFMA_BF16_K32(kf[1][0], qf[mi][0], s1);
        s1 = MFMA_BF16_K32(kf[1][1], qf[mi][1], s1);
        // P A-frag (16x16x32 f16): lane holds keys kk*32+quad*8+0..7 for q=l16
        union { f16x8 v; unsigned int d[4]; } pu;
        pu.d[0] = pkrtz_bits(EXP2F(s0[0]), EXP2F(s0[1]));
        pu.d[1] = pkrtz_bits(EXP2F(s0[2]), EXP2F(s0[3]));
        pu.d[2] = pkrtz_bits(EXP2F(s1[0]), EXP2F(s1[1]));
        pu.d[3] = pkrtz_bits(EXP2F(s1[2]), EXP2F(s1[3]));
        lacc[mi] = MFMA_F16_K32(pu.v, ones8.v, lacc[mi]);
#pragma unroll
        for (int nt = 0; nt < 4; nt++)
          o[mi][nt] = MFMA_F16_K32(pu.v, vf[nt], o[mi][nt]);
      }
    }
  }

  const int h = bh & 15, b = bh >> 4;
#pragma unroll
  for (int mi = 0; mi < 4; mi++) {
    float inv[4];
#pragma unroll
    for (int r = 0; r < 4; r++) inv[r] = 1.f / lacc[mi][r];
#pragma unroll
    for (int nt = 0; nt < 4; nt++)
#pragma unroll
      for (int r = 0; r < 4; r++)
        out[((size_t)(b * SEQ + q0 + mi * 16 + quad * 4 + r)) * DIM + h * 64 + nt * 16 + l16] =
            f2bf(o[mi][nt][r] * inv[r]);
  }
}

// ---- proj GEMM: out[8192,1024] fp32 = Ao bf16 @ Wproj^T + bias ----
__global__ __launch_bounds__(256) void gemm_proj(
    const unsigned short* __restrict__ A,
    const unsigned short* __restrict__ W,
    float* __restrict__ out,
    const float* __restrict__ bias) {
  const int N = DIM, K = DIM;
  __shared__ unsigned short Al[128 * 32];
  __shared__ unsigned short Wl[128 * 32];
  const int tid  = threadIdx.x;
  const int wave = tid >> 6, lane = tid & 63;
  const int quad = lane >> 4, l16 = lane & 15;
  const int m0 = blockIdx.y * 128, n0 = blockIdx.x * 128;
  const int wr = (wave >> 1) * 64, wc = (wave & 1) * 64;

  f32x4 acc[4][4];
#pragma unroll
  for (int i = 0; i < 4; i++)
#pragma unroll
    for (int j = 0; j < 4; j++) acc[i][j] = (f32x4)0.f;

  const int arow = wave * 16 + (lane >> 2);
  const int acol = (lane & 3) * 8;
  const unsigned short* Ag = A + (size_t)(m0 + arow) * K + acol;
  const unsigned short* Wg = W + (size_t)(n0 + arow) * K + acol;

  for (int kt = 0; kt < K; kt += 32) {
    __syncthreads();
#pragma unroll
    for (int i = 0; i < 2; i++) {
      gload_lds16((const void*)(Ag + (size_t)(i * 64) * K + kt), (void*)&Al[i * 2048 + wave * 512]);
      gload_lds16((const void*)(Wg + (size_t)(i * 64) * K + kt), (void*)&Wl[i * 2048 + wave * 512]);
    }
    __syncthreads();

    bf16x8 af[4], wf[4];
#pragma unroll
    for (int i = 0; i < 4; i++) {
      af[i] = *(const bf16x8*)&Al[(wr + i * 16 + l16) * 32 + quad * 8];
      wf[i] = *(const bf16x8*)&Wl[(wc + i * 16 + l16) * 32 + quad * 8];
    }
#pragma unroll
    for (int i = 0; i < 4; i++)
#pragma unroll
      for (int j = 0; j < 4; j++)
        acc[i][j] = __builtin_amdgcn_mfma_f32_16x16x32_bf16(af[i], wf[j], acc[i][j], 0, 0, 0);
  }

#pragma unroll
  for (int i = 0; i < 4; i++) {
    const int row = m0 + wr + i * 16 + quad * 4;
#pragma unroll
    for (int j = 0; j < 4; j++) {
      const int col = n0 + wc + j * 16 + l16;
      const float bv = bias[col];
#pragma unroll
      for (int r = 0; r < 4; r++)
        out[(size_t)(row + r) * N + col] = acc[i][j][r] + bv;
    }
  }
}

extern "C" void kernel_launch(void* const* d_in, const int* in_sizes, int n_in,
                              void* d_out, int out_size, void* d_ws, size_t ws_size,
                              hipStream_t stream) {
  const float* x      = (const float*)d_in[0];
  const float* w_qkv  = (const float*)d_in[1];
  const float* w_proj = (const float*)d_in[2];
  const float* b_proj = (const float*)d_in[3];
  float* outp = (float*)d_out;

  char* ws = (char*)d_ws;
  unsigned short* xb     = (unsigned short*)(ws);                        // 16 MB
  unsigned short* wqkvb  = (unsigned short*)(ws + (16u << 20));          // 6 MB
  unsigned short* wprojb = (unsigned short*)(ws + (22u << 20));          // 2 MB
  unsigned short* qb     = (unsigned short*)(ws + (24u << 20));          // 16 MB
  unsigned short* kb     = (unsigned short*)(ws + (40u << 20));          // 16 MB
  unsigned short* vtb    = (unsigned short*)(ws + (56u << 20));          // 16 MB (fp16)
  unsigned short* aout   = (unsigned short*)(ws + (72u << 20));          // 16 MB

  const int total4 = (ROWS * DIM + 3 * DIM * DIM + DIM * DIM) / 4;  // 3,145,728
  cast_all<<<total4 / 256, 256, 0, stream>>>(x, w_qkv, w_proj, xb, wqkvb, wprojb);

  gemm_qkv8<1, 8><<<dim3(8, 32), 512, 0, stream>>>(xb, wqkvb, qb, kb, vtb);  // Q,K
  gemm_qkv8<0, 4><<<dim3(4, 32), 512, 0, stream>>>(xb, wqkvb, qb, kb, vtb);  // V
  attn_kernel<<<dim3(64, 8), 256, 0, stream>>>(qb, kb, vtb, aout);
  gemm_proj<<<dim3(8, 64), 256, 0, stream>>>(aout, wprojb, outp, b_proj);
}

// Round 2
// 257.632 us; speedup vs baseline: 1.0257x; 1.0257x over previous
//
#include <hip/hip_runtime.h>
#include <stdint.h>

#define DIM 1024
#define SEQ 2048
#define BATCH 4
#define ROWS (BATCH*SEQ)          /* 8192 */
// attention scale folded into Q: 0.125 * log2(e)
#define QSCALE 0.1803368801111f

typedef __attribute__((ext_vector_type(8))) short bf16x8;   // 8 bf16 in 4 VGPRs
typedef __attribute__((ext_vector_type(4))) float f32x4;
typedef __attribute__((ext_vector_type(8))) _Float16 f16x8;
typedef __attribute__((ext_vector_type(2))) __fp16 fp16x2_raw;  // cvt_pkrtz return type

#if __has_builtin(__builtin_amdgcn_exp2f)
#define EXP2F(x) __builtin_amdgcn_exp2f(x)
#else
#define EXP2F(x) __expf((x) * 0.69314718056f)
#endif

#define MFMA_BF16_K32(a,b,c) __builtin_amdgcn_mfma_f32_16x16x32_bf16(a,b,c,0,0,0)
#define MFMA_F16_K32(a,b,c)  __builtin_amdgcn_mfma_f32_16x16x32_f16(a,b,c,0,0,0)

// ---- fp32 -> bf16 RNE ----
__device__ __forceinline__ unsigned short f2bf(float f) {
  union { float f; unsigned int u; } v; v.f = f;
  unsigned int u = v.u;
  return (unsigned short)((u + 0x7FFFu + ((u >> 16) & 1u)) >> 16);
}

// ---- fp32 -> fp16 RNE (bits) ----
__device__ __forceinline__ unsigned short f2h(float f) {
  union { _Float16 h; unsigned short u; } v;
  v.h = (_Float16)f;
  return v.u;
}

// pack two f32 -> fp16x2 dword (v_cvt_pkrtz_f16_f32), returned as raw bits
__device__ __forceinline__ unsigned int pkrtz_bits(float lo, float hi) {
  union { fp16x2_raw h; unsigned int u; } v;
  v.h = __builtin_amdgcn_cvt_pkrtz(lo, hi);
  return v.u;
}

// ---- async global->LDS, 16B per lane (wave-uniform LDS base + lane*16) ----
__device__ __forceinline__ void gload_lds16(const void* g, void* l) {
  __builtin_amdgcn_global_load_lds(
      (const __attribute__((address_space(1))) unsigned int*)g,
      (__attribute__((address_space(3))) unsigned int*)l,
      16, 0, 0);
}

// ---- fused cast kernel: x (8M) | w_qkv (3M) | w_proj (1M) fp32 -> bf16 ----
__global__ void cast_all(const float* __restrict__ x,
                         const float* __restrict__ wq,
                         const float* __restrict__ wp,
                         unsigned short* __restrict__ xb,
                         unsigned short* __restrict__ wqb,
                         unsigned short* __restrict__ wpb) {
  const int i = (blockIdx.x * blockDim.x + threadIdx.x) * 4;
  const float* src;
  unsigned short* dst;
  int off;
  if (i < ROWS * DIM)                 { src = x;  dst = xb;  off = i; }
  else if (i < ROWS * DIM + 3 * DIM * DIM) { src = wq; dst = wqb; off = i - ROWS * DIM; }
  else                                { src = wp; dst = wpb; off = i - ROWS * DIM - 3 * DIM * DIM; }
  float4 f = *(const float4*)(src + off);
  ushort4 o;
  o.x = f2bf(f.x); o.y = f2bf(f.y); o.z = f2bf(f.z); o.w = f2bf(f.w);
  *(ushort4*)(dst + off) = o;
}

// swapped/normal MFMA helper (SWAP transposes the C fragment)
template<int SWAP>
__device__ __forceinline__ f32x4 mm(bf16x8 a, bf16x8 b, f32x4 c) {
  if constexpr (SWAP) return __builtin_amdgcn_mfma_f32_16x16x32_bf16(b, a, c, 0, 0, 0);
  else                return __builtin_amdgcn_mfma_f32_16x16x32_bf16(a, b, c, 0, 0, 0);
}

// ---- 8-phase 256x256 Q/K GEMM (T2+T3+T4+T5 template, plain HIP) ----
// C[8192, n0..n0+256) = X @ Wqkv^T over K=1024 (16 K-tiles of 64).
// SWAP=1: Q/K columns (n0 in [0,2048)), transposed C frags -> vectorized
//         [bh][n][d] ushort4 writes (Q scaled by QSCALE).
// Per K-tile t: 4 phases x {ds-subtile | 1-2 stage | bar lgkm mfma(16) bar},
// vmcnt(6) once per tile (never 0 in main loop). LDS rows 128B -> XOR
// swizzle chunk^=(row&7), applied as pre-swizzled GLOBAL source + swizzled
// ds_read address (gload_lds writes linearly).
template<int SWAP, int NTX>
__global__ __launch_bounds__(512, 2) void gemm_qkv8(
    const unsigned short* __restrict__ A,    // [8192][1024] bf16
    const unsigned short* __restrict__ W,    // [3072][1024] bf16
    unsigned short* __restrict__ qb,
    unsigned short* __restrict__ kb,
    unsigned short* __restrict__ vtb) {
  constexpr int K = DIM;
  constexpr int NT = K / 64;                 // 16 K-tiles
  constexpr int N0B = SWAP ? 0 : 2048;
  __shared__ unsigned short Al[2][256 * 64]; // 64KB
  __shared__ unsigned short Bl[2][256 * 64]; // 64KB

  const int tid  = threadIdx.x;
  const int wave = tid >> 6, lane = tid & 63;
  const int quad = lane >> 4, l16 = lane & 15;
  const int wm = wave >> 2, wn = wave & 3;   // 2 x 4 wave grid

  // XCD-bijective block swizzle (nwg % 8 == 0 for both grids)
  constexpr int nwg = NTX * 32;
  int id = blockIdx.y * NTX + blockIdx.x;
  id = (id & 7) * (nwg >> 3) + (id >> 3);
  const int bx = id % NTX, by = id / NTX;
  const int m0 = by * 256, n0 = N0B + bx * 256;

  // staging addresses: lane -> (row = wave*8 + lane>>3, src chunk pre-swizzled)
  const int srow8 = lane >> 3;               // 0..7, == (lds row & 7)
  const int schk  = (lane & 7) ^ srow8;      // involution: lds chunk ^ row&7
  const unsigned short* Ast = A + (size_t)(m0 + wave * 8 + srow8) * K + (schk << 3);
  const unsigned short* Bst = W + (size_t)(n0 + wave * 8 + srow8) * K + (schk << 3);

  // one block-wide 64-row slab load: 1 gload_lds per wave (8 rows/wave)
  auto stg = [&](const unsigned short* g, int R0, int kt, unsigned short* l) {
    gload_lds16((const void*)(g + (size_t)R0 * K + kt),
                (void*)(l + (R0 + wave * 8) * 64));
  };
  // swizzled fragment read: row rb+idx*16+l16, k-chunk kk*4+quad
  auto ldf = [&](const unsigned short* base, int rb, int idx, int kk) -> bf16x8 {
    const int r = rb + idx * 16 + l16;
    return *(const bf16x8*)&base[r * 64 + (((kk * 4 + quad) ^ (l16 & 7)) << 3)];
  };

  f32x4 acc[8][4];
#pragma unroll
  for (int i = 0; i < 8; ++i)
#pragma unroll
    for (int j = 0; j < 4; ++j) acc[i][j] = (f32x4)0.f;

  // prologue: tile 0 complete (8 loads, oldest), tile 1 all but B-h1 (6)
  stg(Ast, 0, 0, Al[0]);  stg(Ast, 128, 0, Al[0]);
  stg(Ast, 64, 0, Al[0]); stg(Ast, 192, 0, Al[0]);
  stg(Bst, 0, 0, Bl[0]);  stg(Bst, 64, 0, Bl[0]);
  stg(Bst, 128, 0, Bl[0]); stg(Bst, 192, 0, Bl[0]);
  stg(Ast, 0, 64, Al[1]);  stg(Ast, 128, 64, Al[1]);
  stg(Bst, 0, 64, Bl[1]);  stg(Bst, 64, 64, Bl[1]);
  stg(Ast, 64, 64, Al[1]); stg(Ast, 192, 64, Al[1]);
  asm volatile("s_waitcnt vmcnt(6)" ::: "memory");  // tile 0 landed
  __builtin_amdgcn_s_barrier();

  bf16x8 af[4][2], bf[4][2];
  int buf = 0;
  for (int t = 0; t < NT; ++t, buf ^= 1) {
    const unsigned short* Ac = Al[buf];
    const unsigned short* Bc = Bl[buf];
    unsigned short* Asg = Al[buf];   // tile t+2 reuses current buffer
    unsigned short* Bsg = Bl[buf];
    const int kt2 = (t + 2) * 64;

    // ---------- P1 ----------
#pragma unroll
    for (int mi = 0; mi < 4; ++mi) {
      af[mi][0] = ldf(Ac, wm * 128, mi, 0);
      af[mi][1] = ldf(Ac, wm * 128, mi, 1);
    }
#pragma unroll
    for (int ni = 0; ni < 2; ++ni) {
      bf[ni][0] = ldf(Bc, wn * 64, ni, 0);
      bf[ni][1] = ldf(Bc, wn * 64, ni, 1);
    }
    if (t + 1 < NT) {  // B-h1 of tile t+1 (region free since tile t-1)
      stg(Bst, 128, (t + 1) * 64, Bl[buf ^ 1]);
      stg(Bst, 192, (t + 1) * 64, Bl[buf ^ 1]);
    }
    __builtin_amdgcn_s_barrier();
    asm volatile("s_waitcnt lgkmcnt(0)" ::: "memory");
    __builtin_amdgcn_s_setprio(1);
#pragma unroll
    for (int mi = 0; mi < 4; ++mi)
#pragma unroll
      for (int ni = 0; ni < 2; ++ni)
#pragma unroll
        for (int kk = 0; kk < 2; ++kk)
          acc[mi][ni] = mm<SWAP>(af[mi][kk], bf[ni][kk], acc[mi][ni]);
    __builtin_amdgcn_s_setprio(0);
    __builtin_amdgcn_s_barrier();

    // ---------- P2 ----------
#pragma unroll
    for (int ni = 2; ni < 4; ++ni) {
      bf[ni][0] = ldf(Bc, wn * 64, ni, 0);
      bf[ni][1] = ldf(Bc, wn * 64, ni, 1);
    }
    if (t + 2 < NT) {  // A rows {0-63,128-191}: freed by P1
      stg(Ast, 0, kt2, Asg);
      stg(Ast, 128, kt2, Asg);
    }
    __builtin_amdgcn_s_barrier();
    asm volatile("s_waitcnt lgkmcnt(0)" ::: "memory");
    __builtin_amdgcn_s_setprio(1);
#pragma unroll
    for (int mi = 0; mi < 4; ++mi)
#pragma unroll
      for (int ni = 2; ni < 4; ++ni)
#pragma unroll
        for (int kk = 0; kk < 2; ++kk)
          acc[mi][ni] = mm<SWAP>(af[mi][kk], bf[ni][kk], acc[mi][ni]);
    __builtin_amdgcn_s_setprio(0);
    __builtin_amdgcn_s_barrier();

    // ---------- P3 ----------
#pragma unroll
    for (int mi = 0; mi < 4; ++mi) {
      af[mi][0] = ldf(Ac, wm * 128, mi + 4, 0);
      af[mi][1] = ldf(Ac, wm * 128, mi + 4, 1);
    }
    if (t + 2 < NT) {  // B rows {0-127}: all B freed by P2
      stg(Bst, 0, kt2, Bsg);
      stg(Bst, 64, kt2, Bsg);
    }
    __builtin_amdgcn_s_barrier();
    asm volatile("s_waitcnt lgkmcnt(0)" ::: "memory");
    __builtin_amdgcn_s_setprio(1);
#pragma unroll
    for (int mi = 0; mi < 4; ++mi)
#pragma unroll
      for (int ni = 2; ni < 4; ++ni)
#pragma unroll
        for (int kk = 0; kk < 2; ++kk)
          acc[mi + 4][ni] = mm<SWAP>(af[mi][kk], bf[ni][kk], acc[mi + 4][ni]);
    __builtin_amdgcn_s_setprio(0);
    __builtin_amdgcn_s_barrier();

    // ---------- P4 ----------
    if (t + 2 < NT) {  // A rows {64-127,192-255}: freed by P3
      stg(Ast, 64, kt2, Asg);
      stg(Ast, 192, kt2, Asg);
      asm volatile("s_waitcnt vmcnt(6)" ::: "memory");  // tile t+1 landed
    } else {
      asm volatile("s_waitcnt vmcnt(0)" ::: "memory");
    }
    __builtin_amdgcn_s_barrier();
    __builtin_amdgcn_s_setprio(1);
#pragma unroll
    for (int mi = 0; mi < 4; ++mi)
#pragma unroll
      for (int ni = 0; ni < 2; ++ni)
#pragma unroll
        for (int kk = 0; kk < 2; ++kk)
          acc[mi + 4][ni] = mm<SWAP>(af[mi][kk], bf[ni][kk], acc[mi + 4][ni]);
    __builtin_amdgcn_s_setprio(0);
    __builtin_amdgcn_s_barrier();
  }

  // ---------- epilogue ----------
  if constexpr (SWAP) {
    // transposed frags: lane col=l16 -> token, row=quad*4+r -> feature
    const float sc = (n0 < 1024) ? QSCALE : 1.f;
    unsigned short* base = (n0 < 1024) ? qb : kb;
#pragma unroll
    for (int mi = 0; mi < 8; ++mi) {
      const int tok = m0 + wm * 128 + mi * 16 + l16;
      const int b = tok >> 11, n = tok & 2047;
#pragma unroll
      for (int ni = 0; ni < 4; ++ni) {
        const int f0 = n0 + wn * 64 + ni * 16 + quad * 4;
        const int h = (f0 >> 6) & 15, d = f0 & 63;
        ushort4 o4;
        o4.x = f2bf(acc[mi][ni][0] * sc);
        o4.y = f2bf(acc[mi][ni][1] * sc);
        o4.z = f2bf(acc[mi][ni][2] * sc);
        o4.w = f2bf(acc[mi][ni][3] * sc);
        *(ushort4*)&base[((size_t)(b * 16 + h) * SEQ + n) * 64 + d] = o4;
      }
    }
  } else {
    // normal frags: row=quad*4+r -> token, col=l16 -> feature; V^T fp16
#pragma unroll
    for (int mi = 0; mi < 8; ++mi) {
      const int row = m0 + wm * 128 + mi * 16 + quad * 4;
      const int b = row >> 11, n = row & 2047;
#pragma unroll
      for (int ni = 0; ni < 4; ++ni) {
        const int col = n0 + wn * 64 + ni * 16 + l16;
        const int h = (col >> 6) & 15, d = col & 63;
        ushort4 o4;
        o4.x = f2h(acc[mi][ni][0]); o4.y = f2h(acc[mi][ni][1]);
        o4.z = f2h(acc[mi][ni][2]); o4.w = f2h(acc[mi][ni][3]);
        *(ushort4*)&vtb[((size_t)(b * 16 + h) * 64 + d) * SEQ + n] = o4;
      }
    }
  }
}

// ---- 8-phase 128x256 GEMM template (V-gemm and proj): full-occupancy grids.
// BM=128, BN=256, BK=64, 512 threads (2m x 4n waves), per-wave 64x64 output
// (acc[4][4]).  LDS = 2*(A 16KB + B 32KB) = 96KB -> 1 block/CU; grid 4x64 =
// 256 blocks = exactly one round on 256 CUs.
// Region granularity is 32 rows; each staging instr covers TWO 32-row regions
// via wave-halves (waves 0-3 -> R0, waves 4-7 -> R1), 8 rows/wave.
// Partition per K-tile (6 staging instr): t+1 gets B{128-159,192-223} +
// B{160-191,224-255} at P1 (-> buf^1, whole buffer free); t+2 gets
// A{0-31,64-95} at P2 (freed P1), B{0-31,64-95}+B{32-63,96-127} at P3
// (freed P1/P2), A{32-63,96-127} at P4 (freed P3).  vmcnt(4) once per tile.
// EPI=0: V^T fp16 [bh][d][n] writes.  EPI=1: fp32 out + bias.
template<int EPI>
__global__ __launch_bounds__(512, 2) void gemm8_128x256(
    const unsigned short* __restrict__ A,    // [8192][1024] bf16
    const unsigned short* __restrict__ W,    // [1024][1024] bf16 (pre-offset)
    unsigned short* __restrict__ vtb,        // EPI=0
    float* __restrict__ outp,                // EPI=1
    const float* __restrict__ bias) {        // EPI=1
  constexpr int K = DIM;
  constexpr int NT = K / 64;                 // 16 K-tiles
  __shared__ unsigned short Al[2][128 * 64]; // 32KB
  __shared__ unsigned short Bl[2][256 * 64]; // 64KB

  const int tid  = threadIdx.x;
  const int wave = tid >> 6, lane = tid & 63;
  const int quad = lane >> 4, l16 = lane & 15;
  const int wm = wave >> 2, wn = wave & 3;   // 2 x 4 wave grid

  // XCD-bijective swizzle, nwg = 256
  int id = blockIdx.y * 4 + blockIdx.x;
  id = (id & 7) * 32 + (id >> 3);
  const int bx = id & 3, by = id >> 2;
  const int m0 = by * 128, n0 = bx * 256;

  const int srow8 = lane >> 3;               // 0..7
  const int schk  = (lane & 7) ^ srow8;      // pre-swizzled source chunk
  const unsigned short* Ast = A + (size_t)(m0 + srow8) * K + (schk << 3);
  const unsigned short* Bst = W + (size_t)(n0 + srow8) * K + (schk << 3);

  // pair-stage: waves 0-3 cover rows [R0,R0+32), waves 4-7 [R1,R1+32)
  auto stgA = [&](int kt, unsigned short* l, int R0, int R1) {
    const int rs = (wave < 4 ? R0 : R1) + (wave & 3) * 8;
    gload_lds16((const void*)(Ast + (size_t)rs * K + kt), (void*)(l + rs * 64));
  };
  auto stgB = [&](int kt, unsigned short* l, int R0, int R1) {
    const int rs = (wave < 4 ? R0 : R1) + (wave & 3) * 8;
    gload_lds16((const void*)(Bst + (size_t)rs * K + kt), (void*)(l + rs * 64));
  };
  auto ldf = [&](const unsigned short* base, int rb, int idx, int kk) -> bf16x8 {
    const int r = rb + idx * 16 + l16;
    return *(const bf16x8*)&base[r * 64 + (((kk * 4 + quad) ^ (l16 & 7)) << 3)];
  };

  f32x4 acc[4][4];
#pragma unroll
  for (int i = 0; i < 4; ++i)
#pragma unroll
    for (int j = 0; j < 4; ++j) acc[i][j] = (f32x4)0.f;

  // prologue: tile0 complete (6, oldest), tile1's t+2-set (4)
  stgA(0, Al[0], 0, 64);   stgA(0, Al[0], 32, 96);
  stgB(0, Bl[0], 0, 64);   stgB(0, Bl[0], 32, 96);
  stgB(0, Bl[0], 128, 192); stgB(0, Bl[0], 160, 224);
  stgA(64, Al[1], 0, 64);  stgA(64, Al[1], 32, 96);
  stgB(64, Bl[1], 0, 64);  stgB(64, Bl[1], 32, 96);
  asm volatile("s_waitcnt vmcnt(4)" ::: "memory");  // tile 0 landed
  __builtin_amdgcn_s_barrier();

  bf16x8 af[2][2], bf[4][2];
  int buf = 0;
  for (int t = 0; t < NT; ++t, buf ^= 1) {
    const unsigned short* Ac = Al[buf];
    const unsigned short* Bc = Bl[buf];
    unsigned short* Asg = Al[buf];
    unsigned short* Bsg = Bl[buf];
    const int kt2 = (t + 2) * 64;

    // ---------- P1: af(mi01)+bf(ni01) | stg B-hi(t+1) | mfma mi01 x ni01 ----
#pragma unroll
    for (int i = 0; i < 2; ++i) {
      af[i][0] = ldf(Ac, wm * 64, i, 0);
      af[i][1] = ldf(Ac, wm * 64, i, 1);
    }
#pragma unroll
    for (int ni = 0; ni < 2; ++ni) {
      bf[ni][0] = ldf(Bc, wn * 64, ni, 0);
      bf[ni][1] = ldf(Bc, wn * 64, ni, 1);
    }
    if (t + 1 < NT) {
      stgB((t + 1) * 64, Bl[buf ^ 1], 128, 192);
      stgB((t + 1) * 64, Bl[buf ^ 1], 160, 224);
    }
    __builtin_amdgcn_s_barrier();
    asm volatile("s_waitcnt lgkmcnt(0)" ::: "memory");
    __builtin_amdgcn_s_setprio(1);
#pragma unroll
    for (int mi = 0; mi < 2; ++mi)
#pragma unroll
      for (int ni = 0; ni < 2; ++ni)
#pragma unroll
        for (int kk = 0; kk < 2; ++kk)
          acc[mi][ni] = mm<0>(af[mi][kk], bf[ni][kk], acc[mi][ni]);
    __builtin_amdgcn_s_setprio(0);
    __builtin_amdgcn_s_barrier();

    // ---------- P2: bf(ni23) | stg A0(t+2) | mfma mi01 x ni23 ----
#pragma unroll
    for (int ni = 2; ni < 4; ++ni) {
      bf[ni][0] = ldf(Bc, wn * 64, ni, 0);
      bf[ni][1] = ldf(Bc, wn * 64, ni, 1);
    }
    if (t + 2 < NT) stgA(kt2, Asg, 0, 64);
    __builtin_amdgcn_s_barrier();
    asm volatile("s_waitcnt lgkmcnt(0)" ::: "memory");
    __builtin_amdgcn_s_setprio(1);
#pragma unroll
    for (int mi = 0; mi < 2; ++mi)
#pragma unroll
      for (int ni = 2; ni < 4; ++ni)
#pragma unroll
        for (int kk = 0; kk < 2; ++kk)
          acc[mi][ni] = mm<0>(af[mi][kk], bf[ni][kk], acc[mi][ni]);
    __builtin_amdgcn_s_setprio(0);
    __builtin_amdgcn_s_barrier();

    // ---------- P3: af(mi23) | stg B-lo(t+2) | mfma mi23 x ni23 ----
#pragma unroll
    for (int i = 0; i < 2; ++i) {
      af[i][0] = ldf(Ac, wm * 64, i + 2, 0);
      af[i][1] = ldf(Ac, wm * 64, i + 2, 1);
    }
    if (t + 2 < NT) {
      stgB(kt2, Bsg, 0, 64);
      stgB(kt2, Bsg, 32, 96);
    }
    __builtin_amdgcn_s_barrier();
    asm volatile("s_waitcnt lgkmcnt(0)" ::: "memory");
    __builtin_amdgcn_s_setprio(1);
#pragma unroll
    for (int mi = 0; mi < 2; ++mi)
#pragma unroll
      for (int ni = 2; ni < 4; ++ni)
#pragma unroll
        for (int kk = 0; kk < 2; ++kk)
          acc[mi + 2][ni] = mm<0>(af[mi][kk], bf[ni][kk], acc[mi + 2][ni]);
    __builtin_amdgcn_s_setprio(0);
    __builtin_amdgcn_s_barrier();

    // ---------- P4: stg A1(t+2) + vmcnt | mfma mi23 x ni01 ----
    if (t + 2 < NT) {
      stgA(kt2, Asg, 32, 96);
      asm volatile("s_waitcnt vmcnt(4)" ::: "memory");  // tile t+1 landed
    } else {
      asm volatile("s_waitcnt vmcnt(0)" ::: "memory");
    }
    __builtin_amdgcn_s_barrier();
    __builtin_amdgcn_s_setprio(1);
#pragma unroll
    for (int mi = 0; mi < 2; ++mi)
#pragma unroll
      for (int ni = 0; ni < 2; ++ni)
#pragma unroll
        for (int kk = 0; kk < 2; ++kk)
          acc[mi + 2][ni] = mm<0>(af[mi][kk], bf[ni][kk], acc[mi + 2][ni]);
    __builtin_amdgcn_s_setprio(0);
    __builtin_amdgcn_s_barrier();
  }

  // ---------- epilogue: normal frags, row=quad*4+r token, col=l16 ----
  if constexpr (EPI == 0) {
    // V^T fp16 [bh][d][n]: 4 consecutive tokens per lane -> ushort4
#pragma unroll
    for (int mi = 0; mi < 4; ++mi) {
      const int row = m0 + wm * 64 + mi * 16 + quad * 4;
      const int b = row >> 11, n = row & 2047;
#pragma unroll
      for (int ni = 0; ni < 4; ++ni) {
        const int col = n0 + wn * 64 + ni * 16 + l16;
        const int h = (col >> 6) & 15, d = col & 63;
        ushort4 o4;
        o4.x = f2h(acc[mi][ni][0]); o4.y = f2h(acc[mi][ni][1]);
        o4.z = f2h(acc[mi][ni][2]); o4.w = f2h(acc[mi][ni][3]);
        *(ushort4*)&vtb[((size_t)(b * 16 + h) * 64 + d) * SEQ + n] = o4;
      }
    }
  } else {
    // fp32 out + bias
#pragma unroll
    for (int mi = 0; mi < 4; ++mi) {
      const int row = m0 + wm * 64 + mi * 16 + quad * 4;
#pragma unroll
      for (int ni = 0; ni < 4; ++ni) {
        const int col = n0 + wn * 64 + ni * 16 + l16;
        const float bv = bias[col];
#pragma unroll
        for (int r = 0; r < 4; ++r)
          outp[(size_t)(row + r) * DIM + col] = acc[mi][ni][r] + bv;
      }
    }
  }
}

// ---- flash attention R8: 8 waves x 32 q-rows, 2 blocks/CU (16 waves/CU).
// S^T = K*Q^T with PERMUTED key rows: two 16-key tiles T0={8a+b}, T1={8a+4+b}
// per 32-key group, so lane (quad,l16)'s exp'd C-frags concatenate into the
// exact A-frag of mfma_f32_16x16x32_f16 (keys quad*8+0..7). PV at full K=32
// rate, P never touches LDS. Double-buffered K/V, one barrier/iter.
// Grid (bh=64, qtile=8): same-bh blocks land on one XCD (%8) -> L2 reuse.
__global__ __launch_bounds__(512, 4) void attn_kernel(
    const unsigned short* __restrict__ qb,   // [bh][n][d] bf16, pre-scaled by QSCALE
    const unsigned short* __restrict__ kb,   // [bh][n][d] bf16
    const unsigned short* __restrict__ vtb,  // [bh][d][n] fp16
    unsigned short* __restrict__ out) {      // [8192][1024] bf16
  __shared__ unsigned short Kl[2][64 * 64];  // [key][d], chunk c at c^sK(row), sK=(r&3)|((r>>3&1)<<2)
  __shared__ unsigned short Vl[2][64 * 64];  // [d][key] fp16 bits, chunk c at c^(row&7)

  const int tid  = threadIdx.x;
  const int wave = tid >> 6, lane = tid & 63;
  const int quad = lane >> 4, l16 = lane & 15;
  const int bh    = blockIdx.x;           // 0..63  (XCD affinity)
  const int qtile = blockIdx.y;           // 0..7
  const size_t qkbase = (size_t)bh * SEQ * 64;
  const int q0 = qtile * 256 + wave * 32;

  // Q B-frags: Q[n=l16][k=kk*32+quad*8+j]  (kk = d-half here)
  bf16x8 qf[2][2];
#pragma unroll
  for (int mi = 0; mi < 2; mi++)
#pragma unroll
    for (int kk = 0; kk < 2; kk++)
      qf[mi][kk] = *(const bf16x8*)&qb[qkbase + (size_t)(q0 + mi * 16 + l16) * 64 + kk * 32 + quad * 8];

  f32x4 o[2][4];
#pragma unroll
  for (int mi = 0; mi < 2; mi++)
#pragma unroll
    for (int nt = 0; nt < 4; nt++) o[mi][nt] = (f32x4)0.f;
  f32x4 lacc[2];
#pragma unroll
  for (int mi = 0; mi < 2; mi++) lacc[mi] = (f32x4)0.f;

  union { f16x8 v; unsigned int d[4]; } ones8;
#pragma unroll
  for (int j = 0; j < 4; j++) ones8.d[j] = 0x3C003C00u;  // fp16 1.0 x8

  const unsigned short* Kg = kb + qkbase;
  const unsigned short* Vg = vtb + (size_t)bh * 64 * SEQ;
  const int srow = tid >> 3;   // 0..63 (512 threads cover 64 rows)
  const int schk = tid & 7;
  const int swK = (srow & 3) | (((srow >> 3) & 1) << 2);
  const int swV = srow & 7;

  auto stage = [&](int kt, int b) {
    gload_lds16((const void*)(Kg + (size_t)(kt + srow) * 64 + (schk ^ swK) * 8),
                (void*)&Kl[b][wave * 512]);
    gload_lds16((const void*)(Vg + (size_t)srow * SEQ + kt + (schk ^ swV) * 8),
                (void*)&Vl[b][wave * 512]);
  };

  stage(0, 0);

  const int rbase = ((l16 >> 2) << 3) + (l16 & 3);               // 8a + b
  const int sR = (l16 & 3) | (((l16 >> 2) & 1) << 2);            // K read swizzle

  int buf = 0;
  for (int kt = 0; kt < SEQ; kt += 64, buf ^= 1) {
    __syncthreads();  // tile `buf` staged; prev reads of buf^1 done
    if (kt + 64 < SEQ) stage(kt + 64, buf ^ 1);

#pragma unroll
    for (int kk = 0; kk < 2; kk++) {
      // K A-frags, permuted rows: T gives phys keys kk*32 + 8*(l16>>2) + (l16&3) + 4T
      bf16x8 kf[2][2];
#pragma unroll
      for (int T = 0; T < 2; T++) {
        const int R = kk * 32 + rbase + 4 * T;
        kf[T][0] = *(const bf16x8*)&Kl[buf][R * 64 + ((quad ^ sR) << 3)];
        kf[T][1] = *(const bf16x8*)&Kl[buf][R * 64 + (((4 + quad) ^ sR) << 3)];
      }
      // V B-frags: B[n=d=nt*16+l16][k=key=kk*32+quad*8+j]
      f16x8 vf[4];
#pragma unroll
      for (int nt = 0; nt < 4; nt++) {
        const int vr = nt * 16 + l16;
        vf[nt] = *(const f16x8*)&Vl[buf][vr * 64 + (((kk * 4 + quad) ^ (vr & 7)) << 3)];
      }
#pragma unroll
      for (int mi = 0; mi < 2; mi++) {
        // S^T tiles: C[m -> phys key kk*32+8*quad+r(+4T)][n=q=l16]
        f32x4 s0 = (f32x4)0.f, s1 = (f32x4)0.f;
        s0 = MFMA_BF16_K32(kf[0][0], qf[mi][0], s0);
        s0 = MFMA_BF16_K32(kf[0][1], qf[mi][1], s0);
        s1 = MFMA_BF16_K32(kf[1][0], qf[mi][0], s1);
        s1 = MFMA_BF16_K32(kf[1][1], qf[mi][1], s1);
        // P A-frag (16x16x32 f16): lane holds keys kk*32+quad*8+0..7 for q=l16
        union { f16x8 v; unsigned int d[4]; } pu;
        pu.d[0] = pkrtz_bits(EXP2F(s0[0]), EXP2F(s0[1]));
        pu.d[1] = pkrtz_bits(EXP2F(s0[2]), EXP2F(s0[3]));
        pu.d[2] = pkrtz_bits(EXP2F(s1[0]), EXP2F(s1[1]));
        pu.d[3] = pkrtz_bits(EXP2F(s1[2]), EXP2F(s1[3]));
        lacc[mi] = MFMA_F16_K32(pu.v, ones8.v, lacc[mi]);
#pragma unroll
        for (int nt = 0; nt < 4; nt++)
          o[mi][nt] = MFMA_F16_K32(pu.v, vf[nt], o[mi][nt]);
      }
    }
  }

  const int h = bh & 15, b = bh >> 4;
#pragma unroll
  for (int mi = 0; mi < 2; mi++) {
    float inv[4];
#pragma unroll
    for (int r = 0; r < 4; r++) inv[r] = 1.f / lacc[mi][r];
#pragma unroll
    for (int nt = 0; nt < 4; nt++)
#pragma unroll
      for (int r = 0; r < 4; r++)
        out[((size_t)(b * SEQ + q0 + mi * 16 + quad * 4 + r)) * DIM + h * 64 + nt * 16 + l16] =
            f2bf(o[mi][nt][r] * inv[r]);
  }
}

extern "C" void kernel_launch(void* const* d_in, const int* in_sizes, int n_in,
                              void* d_out, int out_size, void* d_ws, size_t ws_size,
                              hipStream_t stream) {
  const float* x      = (const float*)d_in[0];
  const float* w_qkv  = (const float*)d_in[1];
  const float* w_proj = (const float*)d_in[2];
  const float* b_proj = (const float*)d_in[3];
  float* outp = (float*)d_out;

  char* ws = (char*)d_ws;
  unsigned short* xb     = (unsigned short*)(ws);                        // 16 MB
  unsigned short* wqkvb  = (unsigned short*)(ws + (16u << 20));          // 6 MB
  unsigned short* wprojb = (unsigned short*)(ws + (22u << 20));          // 2 MB
  unsigned short* qb     = (unsigned short*)(ws + (24u << 20));          // 16 MB
  unsigned short* kb     = (unsigned short*)(ws + (40u << 20));          // 16 MB
  unsigned short* vtb    = (unsigned short*)(ws + (56u << 20));          // 16 MB (fp16)
  unsigned short* aout   = (unsigned short*)(ws + (72u << 20));          // 16 MB

  const int total4 = (ROWS * DIM + 3 * DIM * DIM + DIM * DIM) / 4;  // 3,145,728
  cast_all<<<total4 / 256, 256, 0, stream>>>(x, w_qkv, w_proj, xb, wqkvb, wprojb);

  gemm_qkv8<1, 8><<<dim3(8, 32), 512, 0, stream>>>(xb, wqkvb, qb, kb, vtb);  // Q,K
  gemm8_128x256<0><<<dim3(4, 64), 512, 0, stream>>>(
      xb, wqkvb + (size_t)2048 * DIM, vtb, nullptr, nullptr);               // V
  attn_kernel<<<dim3(64, 8), 512, 0, stream>>>(qb, kb, vtb, aout);
  gemm8_128x256<1><<<dim3(4, 64), 512, 0, stream>>>(
      aout, wprojb, nullptr, outp, b_proj);                                 // proj
}